// Round 2
// baseline (363.665 us; speedup 1.0000x reference)
//
#include <hip/hip_runtime.h>

#define TLEN 1000000
#define YS 64
#define XS 50000
#define CHUNK 245              // steps per chunk
#define WARM 32                // warm-up steps (multiple of 8)
#define NWAVES ((TLEN + CHUNK - 1) / CHUNK)   // 4082
#define WPB 4                  // waves per block (256 threads)
#define BSCALE 50000.0f        // pre-scale of b so per-step scale ~ 1 (cancels in normalize)

typedef float v2 __attribute__((ext_vector_type(2)));
typedef float v4 __attribute__((ext_vector_type(4)));

__device__ __forceinline__ float wave_sum(float v) {
#pragma unroll
  for (int off = 32; off; off >>= 1) v += __shfl_xor(v, off, 64);
  return v;
}

__device__ __forceinline__ long clampT(long t) {
  return t > (long)(TLEN - 1) ? (long)(TLEN - 1) : t;
}

template <bool USE_BT>
__device__ __forceinline__ float eload(const float* __restrict__ bsrc, int xt, int lane) {
  // USE_BT path: bT already carries BSCALE. Fallback: scale here.
  return USE_BT ? bsrc[(size_t)xt * YS + lane]
                : bsrc[(size_t)lane * XS + xt] * BSCALE;
}

// One recurrence step at time t using ring slot u.
// LDS bufw holds w_{t-1} (unnormalized carry). er[u] = scaled e_t; sx[u] = x[t+8].
template <bool USE_BT, bool STORE>
__device__ __forceinline__ void one_step(long t, int u, float* bufw,
    const v2 (&a2)[32], float (&er)[8], int (&sx)[8],
    const int* __restrict__ x, const float* __restrict__ bsrc,
    float* __restrict__ out, int lane)
{
  const v4* bv = (const v4*)bufw;
  v2 acc0 = {0.f, 0.f}, acc1 = {0.f, 0.f}, acc2 = {0.f, 0.f}, acc3 = {0.f, 0.f};
#pragma unroll
  for (int k = 0; k < 16; k += 2) {
    v4 q0 = bv[k];       // uniform-address broadcast of w_{t-1}[4k..4k+3]
    v4 q1 = bv[k + 1];
    acc0 += q0.lo * a2[2 * k + 0];
    acc1 += q0.hi * a2[2 * k + 1];
    acc2 += q1.lo * a2[2 * k + 2];
    acc3 += q1.hi * a2[2 * k + 3];
  }
  v2 accp = (acc0 + acc1) + (acc2 + acc3);
  float w = (accp.x + accp.y) * er[u];   // unnormalized carry, scale ~O(1) thanks to BSCALE
  bufw[lane] = w;                        // broadcast source for step t+1 (same-wave DS order)
  // off-critical-path: row normalization for the stored output
  float s = wave_sum(w);
  float r = __builtin_amdgcn_rcpf(s);
  if (STORE) out[(size_t)t * YS + lane] = w * r;
  // refill rings for t+8 / t+16
  er[u] = eload<USE_BT>(bsrc, sx[u], lane);
  sx[u] = x[clampT(t + 16)];
}

template <bool USE_BT, bool STORE>
__device__ __forceinline__ void run_steps(long tstart, int count, float* bufw,
    const v2 (&a2)[32], float (&er)[8], int (&sx)[8],
    const int* __restrict__ x, const float* __restrict__ bsrc,
    float* __restrict__ out, int lane)
{
  int nfull = count & ~7;
  long t = tstart;
  for (int blk = 0; blk < nfull; blk += 8) {
#pragma unroll
    for (int u = 0; u < 8; u++)
      one_step<USE_BT, STORE>(t + u, u, bufw, a2, er, sx, x, bsrc, out, lane);
    t += 8;
  }
  int rem = count & 7;
#pragma unroll
  for (int u = 0; u < 8; u++)
    if (u < rem)
      one_step<USE_BT, STORE>(t + u, u, bufw, a2, er, sx, x, bsrc, out, lane);
}

template <bool USE_BT>
__global__ __launch_bounds__(256, 4) void hmm_fwd(
    const int* __restrict__ x, const float* __restrict__ A,
    const float* __restrict__ pi, const float* __restrict__ bsrc,
    float* __restrict__ out)
{
  __shared__ __align__(16) float buf[WPB][YS];
  int wslot = threadIdx.x >> 6;
  int wv = blockIdx.x * WPB + wslot;
  int lane = threadIdx.x & 63;
  if (wv >= NWAVES) return;
  float* bufw = buf[wslot];

  // transition column pairs: a2[i] = (A[2i][lane], A[2i+1][lane])
  v2 a2[32];
#pragma unroll
  for (int i = 0; i < 32; i++) {
    a2[i].x = A[(2 * i + 0) * YS + lane];
    a2[i].y = A[(2 * i + 1) * YS + lane];
  }

  long t0 = (long)wv * CHUNK;
  long tend = t0 + CHUNK;
  if (tend > TLEN) tend = TLEN;

  float w0;
  long ts;
  if (wv == 0) {
    float e0 = eload<USE_BT>(bsrc, x[0], lane);
    float v = e0 * pi[lane];
    float s = wave_sum(v);
    w0 = v * __builtin_amdgcn_rcpf(s);
    out[lane] = w0;            // row 0
    ts = 1;
  } else {
    w0 = 1.0f / 64.0f;         // uniform start; warm-up forgets it
    ts = t0 - WARM;
  }
  bufw[lane] = w0;

  // prologue rings: e for [ts, ts+8), x for [ts+8, ts+16)
  float er[8];
  int sx[8];
#pragma unroll
  for (int u = 0; u < 8; u++) {
    int xt = x[clampT(ts + u)];
    er[u] = eload<USE_BT>(bsrc, xt, lane);
    sx[u] = x[clampT(ts + 8 + u)];
  }

  if (wv == 0) {
    run_steps<USE_BT, true>(1, (int)(tend - 1), bufw, a2, er, sx, x, bsrc, out, lane);
  } else {
    run_steps<USE_BT, false>(ts, WARM, bufw, a2, er, sx, x, bsrc, out, lane);
    run_steps<USE_BT, true>(t0, (int)(tend - t0), bufw, a2, er, sx, x, bsrc, out, lane);
  }
}

// 64x64-tile transpose of b (YS x XS) into bT (XS x YS), pre-scaled by BSCALE
__global__ __launch_bounds__(256) void transpose_b(
    const float* __restrict__ b, float* __restrict__ bT)
{
  __shared__ float tile[64][65];
  int x0 = blockIdx.x << 6;
  int lane = threadIdx.x & 63;
  int w = threadIdx.x >> 6;   // 0..3
  int xg = x0 + lane;
#pragma unroll
  for (int yy = 0; yy < 64; yy += 4) {
    int y = yy + w;
    tile[y][lane] = (xg < XS) ? b[(size_t)y * XS + xg] : 0.f;
  }
  __syncthreads();
#pragma unroll
  for (int xx = 0; xx < 64; xx += 4) {
    int xcur = x0 + xx + w;
    if (xcur < XS) bT[(size_t)xcur * YS + lane] = tile[lane][xx + w] * BSCALE;
  }
}

extern "C" void kernel_launch(void* const* d_in, const int* in_sizes, int n_in,
                              void* d_out, int out_size, void* d_ws, size_t ws_size,
                              hipStream_t stream)
{
  const int*   x  = (const int*)d_in[0];
  const float* A  = (const float*)d_in[1];
  const float* b  = (const float*)d_in[2];
  const float* pi = (const float*)d_in[3];
  float* out = (float*)d_out;

  const size_t bt_bytes = (size_t)XS * YS * sizeof(float);
  int blocks = (NWAVES + WPB - 1) / WPB;

  if (ws_size >= bt_bytes) {
    float* bT = (float*)d_ws;
    int tblocks = (XS + 63) / 64;
    transpose_b<<<tblocks, 256, 0, stream>>>(b, bT);
    hmm_fwd<true><<<blocks, 256, 0, stream>>>(x, A, pi, bT, out);
  } else {
    hmm_fwd<false><<<blocks, 256, 0, stream>>>(x, A, pi, b, out);
  }
}

// Round 3
// 121.626 us; speedup vs baseline: 2.9900x; 2.9900x over previous
//
#include <hip/hip_runtime.h>
#include <hip/hip_bf16.h>

#define TLEN 1000000
#define YS 64
#define XS 50000
#define CHUNK 32
#define WARM 32
#define SPAN (CHUNK + WARM)                    // 64, even (unroll-2)
#define NCHUNK ((TLEN + CHUNK - 1) / CHUNK)    // 31250
#define RPW 16                                 // chunks (MFMA rows) per wave
#define NW ((NCHUNK + RPW - 1) / RPW)          // 1954
#define WPB 4
#define NBLK ((NW + WPB - 1) / WPB)            // 489
#define BSCALE ((float)XS)                     // keeps per-step scale ~1 (cancels in normalize)

typedef float f32x4 __attribute__((ext_vector_type(4)));
typedef short bf16x8 __attribute__((ext_vector_type(8)));
typedef unsigned int u32x4 __attribute__((ext_vector_type(4)));

__device__ __forceinline__ unsigned cvtpk(float lo, float hi) {
  unsigned r;
  asm("v_cvt_pk_bf16_f32 %0, %1, %2" : "=v"(r) : "v"(lo), "v"(hi));
  return r;
}
__device__ __forceinline__ unsigned short f2bf_rne(float f) {
  unsigned u = __float_as_uint(f);
  unsigned r = (u + 0x7FFFu + ((u >> 16) & 1u)) >> 16;
  return (unsigned short)r;
}
__device__ __forceinline__ float bf2f(unsigned short u) {
  return __uint_as_float(((unsigned)u) << 16);
}
__device__ __forceinline__ int clamp01(int t) {
  t = t < 0 ? 0 : t;
  return t > (TLEN - 1) ? (TLEN - 1) : t;
}

template <bool USE_BT>
__device__ __forceinline__ float eget(const float* __restrict__ bsrc, int xt, int c) {
  return USE_BT ? bsrc[(size_t)xt * YS + c]
                : bsrc[(size_t)c * XS + xt] * BSCALE;
}

template <bool USE_BT>
__global__ __launch_bounds__(256, 2) void hmm_fwd(
    const int* __restrict__ x, const float* __restrict__ A,
    const float* __restrict__ pi, const float* __restrict__ bsrc,
    float* __restrict__ out)
{
  __shared__ __align__(16) float wlds[WPB][16][68];   // padded: 68*4B = 17 banks/row
  const int wslot = threadIdx.x >> 6;
  const int wv = blockIdx.x * WPB + wslot;
  const int lane = threadIdx.x & 63;
  if (wv >= NW) return;
  const int g = lane >> 4, c15 = lane & 15;
  float (*wrow)[68] = wlds[wslot];

  // ---- B fragments: transition in bf16 hi/lo split (residual kills systematic bias)
  // B-layout (16x16x32): col = lane&15, k = (lane>>4)*8 + j  (+32h for k-half h)
  bf16x8 Bhi[2][4], Blo[2][4];
#pragma unroll
  for (int h = 0; h < 2; h++)
#pragma unroll
    for (int nt = 0; nt < 4; nt++) {
      bf16x8 bh, bl;
#pragma unroll
      for (int j = 0; j < 8; j++) {
        int k = 32 * h + g * 8 + j;
        int c = 16 * nt + c15;
        float av = A[k * YS + c];
        unsigned short hb = f2bf_rne(av);
        bh[j] = (short)hb;
        bl[j] = (short)f2bf_rne(av - bf2f(hb));
      }
      Bhi[h][nt] = bh; Blo[h][nt] = bl;
    }

  // ---- per-row (chunk) time bases; row r = g*4 + j (C/D layout row mapping)
  const int c0 = wv * RPW;
  int tj[4]; float* op[4];
#pragma unroll
  for (int j = 0; j < 4; j++) {
    tj[j] = (c0 + g * 4 + j) * CHUNK - WARM;
    op[j] = (float*)((char*)out + (long)tj[j] * 256) + c15;
  }

  // init carry (uniform; warm-up forgets it)
#pragma unroll
  for (int j = 0; j < 4; j++)
#pragma unroll
    for (int nt = 0; nt < 4; nt++)
      wrow[g * 4 + j][16 * nt + c15] = 1.0f;

  // chunk-0 exact init vector: o = pi * e0 (unnormalized; store normalizes)
  float o[4];
  {
    int x0 = x[0];
#pragma unroll
    for (int nt = 0; nt < 4; nt++) {
      int c = 16 * nt + c15;
      o[nt] = pi[c] * eget<USE_BT>(bsrc, x0, c);
    }
  }
  const bool isw0 = (wv == 0);

  // ---- prefetch rings: e for steps s, s+1; x-values for steps s+2, s+3
  float e0r[4][4], e1r[4][4]; int xb0[4], xb1[4];
#pragma unroll
  for (int j = 0; j < 4; j++) {
    int xt0 = x[clamp01(tj[j] + 0)];
    int xt1 = x[clamp01(tj[j] + 1)];
#pragma unroll
    for (int nt = 0; nt < 4; nt++) {
      int c = 16 * nt + c15;
      e0r[j][nt] = eget<USE_BT>(bsrc, xt0, c);
      e1r[j][nt] = eget<USE_BT>(bsrc, xt1, c);
    }
    xb0[j] = x[clamp01(tj[j] + 2)];
    xb1[j] = x[clamp01(tj[j] + 3)];
  }

  const f32x4 z4 = {0.f, 0.f, 0.f, 0.f};

  auto stepf = [&](int s, float (&ecur)[4][4], int (&xcur)[4]) {
    // A-frags (carry) from LDS: row = lane&15, k = g*8+j (+32 for half 1)
    const f32x4* wr = (const f32x4*)&wrow[c15][0];
    f32x4 q0 = wr[2 * g];       // h0 j0..3
    f32x4 q1 = wr[2 * g + 1];   // h0 j4..7
    f32x4 q2 = wr[2 * g + 8];   // h1 j0..3
    f32x4 q3 = wr[2 * g + 9];   // h1 j4..7
    union { u32x4 u; bf16x8 b; } ua0, ua1;
    ua0.u = (u32x4){cvtpk(q0.x, q0.y), cvtpk(q0.z, q0.w), cvtpk(q1.x, q1.y), cvtpk(q1.z, q1.w)};
    ua1.u = (u32x4){cvtpk(q2.x, q2.y), cvtpk(q2.z, q2.w), cvtpk(q3.x, q3.y), cvtpk(q3.z, q3.w)};
    bf16x8 a0 = ua0.b, a1 = ua1.b;

    f32x4 C[4];
#pragma unroll
    for (int nt = 0; nt < 4; nt++) {
      f32x4 c = __builtin_amdgcn_mfma_f32_16x16x32_bf16(a0, Bhi[0][nt], z4, 0, 0, 0);
      c = __builtin_amdgcn_mfma_f32_16x16x32_bf16(a0, Blo[0][nt], c, 0, 0, 0);
      c = __builtin_amdgcn_mfma_f32_16x16x32_bf16(a1, Bhi[1][nt], c, 0, 0, 0);
      c = __builtin_amdgcn_mfma_f32_16x16x32_bf16(a1, Blo[1][nt], c, 0, 0, 0);
      C[nt] = c;
    }

    // w = C * e  (fp32; e applied post-MFMA keeps emissions full precision)
    float w[4][4]; // [nt][j]
#pragma unroll
    for (int nt = 0; nt < 4; nt++)
#pragma unroll
      for (int j = 0; j < 4; j++)
        w[nt][j] = C[nt][j] * ecur[j][nt];

    // chunk 0 (row 0 of wave 0): hold exact init until its t=0
    if (isw0 && s <= WARM) {
#pragma unroll
      for (int nt = 0; nt < 4; nt++)
        w[nt][0] = (lane < 16) ? o[nt] : w[nt][0];
    }

    // store normalized rows (off the carry chain)
    if (s >= WARM) {
#pragma unroll
      for (int j = 0; j < 4; j++) {
        float sum = (w[0][j] + w[1][j]) + (w[2][j] + w[3][j]);
        sum += __shfl_xor(sum, 1);
        sum += __shfl_xor(sum, 2);
        sum += __shfl_xor(sum, 4);
        sum += __shfl_xor(sum, 8);
        float r = __builtin_amdgcn_rcpf(sum);
        if (tj[j] < TLEN) {
#pragma unroll
          for (int nt = 0; nt < 4; nt++)
            op[j][16 * nt] = w[nt][j] * r;
        }
      }
    }

    // carry to LDS for next step's A-frags (wave-private, in-order DS)
#pragma unroll
    for (int j = 0; j < 4; j++)
#pragma unroll
      for (int nt = 0; nt < 4; nt++)
        wrow[g * 4 + j][16 * nt + c15] = w[nt][j];

    // prefetch: e for step s+2 (using x prefetched 2 ago), x for step s+4
#pragma unroll
    for (int j = 0; j < 4; j++) {
      if (USE_BT) {
        const float* pe = bsrc + (size_t)(unsigned)xcur[j] * YS + c15;
#pragma unroll
        for (int nt = 0; nt < 4; nt++) ecur[j][nt] = pe[nt * 16];
      } else {
#pragma unroll
        for (int nt = 0; nt < 4; nt++)
          ecur[j][nt] = bsrc[(size_t)(16 * nt + c15) * XS + xcur[j]] * BSCALE;
      }
      xcur[j] = x[clamp01(tj[j] + 4)];
      tj[j] += 1;
      op[j] += YS;
    }
  };

  for (int s = 0; s < SPAN; s += 2) {
    stepf(s, e0r, xb0);
    stepf(s + 1, e1r, xb1);
  }
}

// 64x64-tile transpose of b (YS x XS) into bT (XS x YS), pre-scaled by BSCALE
__global__ __launch_bounds__(256) void transpose_b(
    const float* __restrict__ b, float* __restrict__ bT)
{
  __shared__ float tile[64][65];
  int x0 = blockIdx.x << 6;
  int lane = threadIdx.x & 63;
  int w = threadIdx.x >> 6;
  int xg = x0 + lane;
#pragma unroll
  for (int yy = 0; yy < 64; yy += 4) {
    int y = yy + w;
    tile[y][lane] = (xg < XS) ? b[(size_t)y * XS + xg] : 0.f;
  }
  __syncthreads();
#pragma unroll
  for (int xx = 0; xx < 64; xx += 4) {
    int xcur = x0 + xx + w;
    if (xcur < XS) bT[(size_t)xcur * YS + lane] = tile[lane][xx + w] * BSCALE;
  }
}

extern "C" void kernel_launch(void* const* d_in, const int* in_sizes, int n_in,
                              void* d_out, int out_size, void* d_ws, size_t ws_size,
                              hipStream_t stream)
{
  const int*   x  = (const int*)d_in[0];
  const float* A  = (const float*)d_in[1];
  const float* b  = (const float*)d_in[2];
  const float* pi = (const float*)d_in[3];
  float* out = (float*)d_out;

  const size_t bt_bytes = (size_t)XS * YS * sizeof(float);

  if (ws_size >= bt_bytes) {
    float* bT = (float*)d_ws;
    int tblocks = (XS + 63) / 64;
    transpose_b<<<tblocks, 256, 0, stream>>>(b, bT);
    hmm_fwd<true><<<NBLK, 256, 0, stream>>>(x, A, pi, bT, out);
  } else {
    hmm_fwd<false><<<NBLK, 256, 0, stream>>>(x, A, pi, b, out);
  }
}

// Round 4
// 96.862 us; speedup vs baseline: 3.7545x; 1.2557x over previous
//
#include <hip/hip_runtime.h>

#define TLEN 1000000
#define YS 64
#define XS 50000
#define CHUNK 32
#define WARM 16
#define SPAN (CHUNK + WARM)                    // 48, multiple of 4
#define NCHUNK ((TLEN + CHUNK - 1) / CHUNK)    // 31250
#define RPW 16                                 // chunks (MFMA rows) per wave
#define NW ((NCHUNK + RPW - 1) / RPW)          // 1954
#define WPB 4
#define NBLK ((NW + WPB - 1) / WPB)            // 489
#define BSCALE ((float)XS)                     // per-step scale ~1; cancels in normalize

typedef float f32x4 __attribute__((ext_vector_type(4)));
typedef short bf16x8 __attribute__((ext_vector_type(8)));
typedef unsigned int u32x4 __attribute__((ext_vector_type(4)));

__device__ __forceinline__ unsigned cvtpk(float lo, float hi) {
  unsigned r;
  asm("v_cvt_pk_bf16_f32 %0, %1, %2" : "=v"(r) : "v"(lo), "v"(hi));
  return r;
}
__device__ __forceinline__ unsigned short f2bf_rne(float f) {
  unsigned u = __float_as_uint(f);
  unsigned r = (u + 0x7FFFu + ((u >> 16) & 1u)) >> 16;
  return (unsigned short)r;
}
__device__ __forceinline__ float bf2f(unsigned short u) {
  return __uint_as_float(((unsigned)u) << 16);
}
__device__ __forceinline__ float bfu_lo(unsigned d) { return __uint_as_float(d << 16); }
__device__ __forceinline__ float bfu_hi(unsigned d) { return __uint_as_float(d & 0xffff0000u); }
__device__ __forceinline__ int clamp01(int t) {
  t = t < 0 ? 0 : t;
  return t > (TLEN - 1) ? (TLEN - 1) : t;
}

template <bool USE_BT>
__global__ __launch_bounds__(256, 2) void hmm_fwd(
    const int* __restrict__ x, const float* __restrict__ A,
    const float* __restrict__ pi, const float* __restrict__ bsrc,
    const unsigned* __restrict__ bpk, float* __restrict__ out)
{
  __shared__ __align__(16) float wlds[WPB][16][68];   // carry; 68-dword row pad
  const int wslot = threadIdx.x >> 6;
  const int wv = blockIdx.x * WPB + wslot;
  const int lane = threadIdx.x & 63;
  if (wv >= NW) return;
  const int g = lane >> 4, c15 = lane & 15;
  float (*wrow)[68] = wlds[wslot];

  // ---- B fragments: transition bf16 hi/lo split (removes systematic quant bias)
  bf16x8 Bhi[2][4], Blo[2][4];
#pragma unroll
  for (int h = 0; h < 2; h++)
#pragma unroll
    for (int nt = 0; nt < 4; nt++) {
      bf16x8 bh, bl;
#pragma unroll
      for (int j = 0; j < 8; j++) {
        int k = 32 * h + g * 8 + j;
        int c = 16 * nt + c15;
        float av = A[k * YS + c];
        unsigned short hb = f2bf_rne(av);
        bh[j] = (short)hb;
        bl[j] = (short)f2bf_rne(av - bf2f(hb));
      }
      Bhi[h][nt] = bh; Blo[h][nt] = bl;
    }

  // ---- per-row time bases (row r = 4g + j)
  const int c0 = wv * RPW;
  int tj[4]; float* op[4];
#pragma unroll
  for (int j = 0; j < 4; j++) {
    tj[j] = (c0 + g * 4 + j) * CHUNK - WARM;
    op[j] = out + (long)tj[j] * YS + c15;
  }

  // init carry (uniform; warm-up forgets it)
#pragma unroll
  for (int j = 0; j < 4; j++)
#pragma unroll
    for (int nt = 0; nt < 4; nt++)
      wrow[g * 4 + j][16 * nt + c15] = 1.0f;

  // chunk-0 exact fp32 init: o = pi * e0 * BSCALE (normalized at store)
  float o[4];
  {
    int x0v = x[0];
#pragma unroll
    for (int nt = 0; nt < 4; nt++) {
      int c = 16 * nt + c15;
      o[nt] = pi[c] * bsrc[(size_t)c * XS + x0v] * BSCALE;
    }
  }
  const bool isw0 = (wv == 0);

  // packed-e loader: d0 = bf16(cols c15 | c15+16), d1 = bf16(cols c15+32 | c15+48)
  auto eload2 = [&](int xt, unsigned& d0, unsigned& d1) {
    if (USE_BT) {
      const unsigned* p = bpk + (size_t)(unsigned)xt * 32 + c15;
      d0 = p[0]; d1 = p[16];
    } else {
      float e0 = bsrc[(size_t)(c15 +  0) * XS + xt] * BSCALE;
      float e1 = bsrc[(size_t)(c15 + 16) * XS + xt] * BSCALE;
      float e2 = bsrc[(size_t)(c15 + 32) * XS + xt] * BSCALE;
      float e3 = bsrc[(size_t)(c15 + 48) * XS + xt] * BSCALE;
      d0 = cvtpk(e0, e1); d1 = cvtpk(e2, e3);
    }
  };

  // ---- prefetch rings: e packed 4 steps deep; x values 4 steps beyond that
  unsigned er[4][4][2]; int xv[4][4];
#pragma unroll
  for (int u = 0; u < 4; u++)
#pragma unroll
    for (int j = 0; j < 4; j++) {
      eload2(x[clamp01(tj[j] + u)], er[u][j][0], er[u][j][1]);
      xv[u][j] = x[clamp01(tj[j] + u + 4)];
    }

  const f32x4 z4 = {0.f, 0.f, 0.f, 0.f};

  auto stepf = [&](int sabs, int u) {
    // A-frags (carry) from LDS: row = c15, k = 8g+j (+32 for half 1)
    const f32x4* wr = (const f32x4*)&wrow[c15][0];
    f32x4 q0 = wr[2 * g];
    f32x4 q1 = wr[2 * g + 1];
    f32x4 q2 = wr[2 * g + 8];
    f32x4 q3 = wr[2 * g + 9];
    union { u32x4 u4; bf16x8 b; } ua0, ua1;
    ua0.u4 = (u32x4){cvtpk(q0.x, q0.y), cvtpk(q0.z, q0.w), cvtpk(q1.x, q1.y), cvtpk(q1.z, q1.w)};
    ua1.u4 = (u32x4){cvtpk(q2.x, q2.y), cvtpk(q2.z, q2.w), cvtpk(q3.x, q3.y), cvtpk(q3.z, q3.w)};
    bf16x8 a0 = ua0.b, a1 = ua1.b;

    f32x4 C[4];
#pragma unroll
    for (int nt = 0; nt < 4; nt++) {
      f32x4 c = __builtin_amdgcn_mfma_f32_16x16x32_bf16(a0, Bhi[0][nt], z4, 0, 0, 0);
      c = __builtin_amdgcn_mfma_f32_16x16x32_bf16(a0, Blo[0][nt], c, 0, 0, 0);
      c = __builtin_amdgcn_mfma_f32_16x16x32_bf16(a1, Bhi[1][nt], c, 0, 0, 0);
      c = __builtin_amdgcn_mfma_f32_16x16x32_bf16(a1, Blo[1][nt], c, 0, 0, 0);
      C[nt] = c;
    }

    // w = C * e (e unpacked from bf16 pairs)
    float w[4][4]; // [nt][j]
#pragma unroll
    for (int j = 0; j < 4; j++) {
      unsigned d0 = er[u][j][0], d1 = er[u][j][1];
      w[0][j] = C[0][j] * bfu_lo(d0);
      w[1][j] = C[1][j] * bfu_hi(d0);
      w[2][j] = C[2][j] * bfu_lo(d1);
      w[3][j] = C[3][j] * bfu_hi(d1);
    }

    // chunk 0 (row 0 of wave 0): hold exact init until its t=0
    if (isw0 && sabs <= WARM) {
#pragma unroll
      for (int nt = 0; nt < 4; nt++)
        w[nt][0] = (lane < 16) ? o[nt] : w[nt][0];
    }

    // store normalized rows (off the carry chain)
    if (sabs >= WARM) {
#pragma unroll
      for (int j = 0; j < 4; j++) {
        float sum = (w[0][j] + w[1][j]) + (w[2][j] + w[3][j]);
        sum += __shfl_xor(sum, 1);
        sum += __shfl_xor(sum, 2);
        sum += __shfl_xor(sum, 4);
        sum += __shfl_xor(sum, 8);
        float r = __builtin_amdgcn_rcpf(sum);
        if (tj[j] < TLEN) {
#pragma unroll
          for (int nt = 0; nt < 4; nt++)
            op[j][16 * nt] = w[nt][j] * r;
        }
      }
    }

    // carry to LDS for next step's A-frags (wave-private, in-order DS)
#pragma unroll
    for (int j = 0; j < 4; j++)
#pragma unroll
      for (int nt = 0; nt < 4; nt++)
        wrow[g * 4 + j][16 * nt + c15] = w[nt][j];

    // refill rings: e for step sabs+4 (x known 4 steps early), x for sabs+8
#pragma unroll
    for (int j = 0; j < 4; j++) {
      eload2(xv[u][j], er[u][j][0], er[u][j][1]);
      xv[u][j] = x[clamp01(tj[j] + 8)];
      tj[j] += 1;
      op[j] += YS;
    }
  };

  for (int s = 0; s < SPAN; s += 4) {
    stepf(s + 0, 0);
    stepf(s + 1, 1);
    stepf(s + 2, 2);
    stepf(s + 3, 3);
  }
}

// transpose+pack b (YS x XS f32) -> bpk (XS x 32 dwords of paired bf16), pre-scaled
__global__ __launch_bounds__(256) void pack_b(
    const float* __restrict__ b, unsigned* __restrict__ bpk)
{
  __shared__ float tile[64][65];
  int x0 = blockIdx.x << 6;
  int lane = threadIdx.x & 63;
  int w = threadIdx.x >> 6;
  int xg = x0 + lane;
#pragma unroll
  for (int yy = 0; yy < 64; yy += 4) {
    int y = yy + w;
    tile[y][lane] = (xg < XS) ? b[(size_t)y * XS + xg] * BSCALE : 0.f;
  }
  __syncthreads();
  int c15 = threadIdx.x & 15;
  int p = (threadIdx.x >> 4) & 1;
  int xo = threadIdx.x >> 5;          // 0..7
#pragma unroll
  for (int pass = 0; pass < 8; pass++) {
    int xl = pass * 8 + xo;
    int xcur = x0 + xl;
    if (xcur < XS) {
      unsigned dw = cvtpk(tile[c15 + 32 * p][xl], tile[c15 + 32 * p + 16][xl]);
      bpk[(size_t)xcur * 32 + p * 16 + c15] = dw;
    }
  }
}

extern "C" void kernel_launch(void* const* d_in, const int* in_sizes, int n_in,
                              void* d_out, int out_size, void* d_ws, size_t ws_size,
                              hipStream_t stream)
{
  const int*   x  = (const int*)d_in[0];
  const float* A  = (const float*)d_in[1];
  const float* b  = (const float*)d_in[2];
  const float* pi = (const float*)d_in[3];
  float* out = (float*)d_out;

  const size_t bpk_bytes = (size_t)XS * 32 * sizeof(unsigned);  // 6.4 MB

  if (ws_size >= bpk_bytes) {
    unsigned* bpk = (unsigned*)d_ws;
    int tblocks = (XS + 63) / 64;
    pack_b<<<tblocks, 256, 0, stream>>>(b, bpk);
    hmm_fwd<true><<<NBLK, 256, 0, stream>>>(x, A, pi, b, bpk, out);
  } else {
    hmm_fwd<false><<<NBLK, 256, 0, stream>>>(x, A, pi, b, nullptr, out);
  }
}

// Round 5
// 88.364 us; speedup vs baseline: 4.1156x; 1.0962x over previous
//
#include <hip/hip_runtime.h>

#define TLEN 1000000
#define YS 64
#define XS 50000
#define CHUNK 32
#define WARM 16
#define SPAN (CHUNK + WARM)                    // 48, multiple of 4
#define NCHUNK ((TLEN + CHUNK - 1) / CHUNK)    // 31250
#define RPW 16                                 // chunks (MFMA rows) per wave
#define NW ((NCHUNK + RPW - 1) / RPW)          // 1954
#define WPB 4
#define NBLK ((NW + WPB - 1) / WPB)            // 489
#define BSCALE ((float)XS)                     // per-step scale ~1; cancels in normalize

typedef float f32x4 __attribute__((ext_vector_type(4)));
typedef short bf16x8 __attribute__((ext_vector_type(8)));
typedef unsigned int u32x4 __attribute__((ext_vector_type(4)));
typedef unsigned int u32x2 __attribute__((ext_vector_type(2)));
typedef int i32x4 __attribute__((ext_vector_type(4)));

__device__ __forceinline__ unsigned cvtpk(float lo, float hi) {
  unsigned r;
  asm("v_cvt_pk_bf16_f32 %0, %1, %2" : "=v"(r) : "v"(lo), "v"(hi));
  return r;
}
__device__ __forceinline__ unsigned short f2bf_rne(float f) {
  unsigned u = __float_as_uint(f);
  unsigned r = (u + 0x7FFFu + ((u >> 16) & 1u)) >> 16;
  return (unsigned short)r;
}
__device__ __forceinline__ float bf2f(unsigned short u) {
  return __uint_as_float(((unsigned)u) << 16);
}
__device__ __forceinline__ float bfu_lo(unsigned d) { return __uint_as_float(d << 16); }
__device__ __forceinline__ float bfu_hi(unsigned d) { return __uint_as_float(d & 0xffff0000u); }
__device__ __forceinline__ int clamp01(int t) {
  t = t < 0 ? 0 : t;
  return t > (TLEN - 1) ? (TLEN - 1) : t;
}
__device__ __forceinline__ int clampB(int t) {   // aligned int4 base clamp
  t = t < 0 ? 0 : t;
  return t > (TLEN - 4) ? (TLEN - 4) : t;
}

template <bool USE_BT>
__global__ __launch_bounds__(256, 2) void hmm_fwd(
    const int* __restrict__ x, const float* __restrict__ A,
    const float* __restrict__ pi, const float* __restrict__ bsrc,
    const unsigned* __restrict__ bpk, float* __restrict__ out)
{
  __shared__ __align__(16) float wlds[WPB][16][68];   // carry; rows 16B-aligned (272B)
  const int wslot = threadIdx.x >> 6;
  const int wv = blockIdx.x * WPB + wslot;
  const int lane = threadIdx.x & 63;
  if (wv >= NW) return;
  const int g = lane >> 4, c15 = lane & 15;   // MFMA A/C layout coords
  const int rr = lane >> 2, qq = lane & 3;    // store layout coords
  float (*wrow)[68] = wlds[wslot];

  // ---- B fragments: transition bf16 hi/lo split (removes systematic quant bias)
  bf16x8 Bhi[2][4], Blo[2][4];
#pragma unroll
  for (int h = 0; h < 2; h++)
#pragma unroll
    for (int nt = 0; nt < 4; nt++) {
      bf16x8 bh, bl;
#pragma unroll
      for (int j = 0; j < 8; j++) {
        int k = 32 * h + g * 8 + j;
        int c = 16 * nt + c15;
        float av = A[k * YS + c];
        unsigned short hb = f2bf_rne(av);
        bh[j] = (short)hb;
        bl[j] = (short)f2bf_rne(av - bf2f(hb));
      }
      Bhi[h][nt] = bh; Blo[h][nt] = bl;
    }

  const int c0 = wv * RPW;

  // store-side per-lane time cursor: row rr, time = (c0+rr)*CHUNK - WARM + sabs
  int trow = (c0 + rr) * CHUNK - WARM;

  // init carry (uniform; warm-up forgets it)
#pragma unroll
  for (int j = 0; j < 4; j++)
#pragma unroll
    for (int nt = 0; nt < 4; nt++)
      wrow[g * 4 + j][16 * nt + c15] = 1.0f;

  // chunk-0 exact fp32 init (C-layout lanes): o = pi * e0 * BSCALE
  float o[4];
  {
    int x0v = x[0];
#pragma unroll
    for (int nt = 0; nt < 4; nt++) {
      int c = 16 * nt + c15;
      o[nt] = pi[c] * bsrc[(size_t)c * XS + x0v] * BSCALE;
    }
  }
  const bool isw0 = (wv == 0);

  // packed-e loader: one dwordx2; d0 = bf16(c15|c15+16), d1 = bf16(c15+32|c15+48)
  auto eload2 = [&](int xt, unsigned& d0, unsigned& d1) {
    if (USE_BT) {
      u32x2 d = *(const u32x2*)(bpk + (size_t)(unsigned)xt * 32 + 2 * c15);
      d0 = d.x; d1 = d.y;
    } else {
      float e0 = bsrc[(size_t)(c15 +  0) * XS + xt] * BSCALE;
      float e1 = bsrc[(size_t)(c15 + 16) * XS + xt] * BSCALE;
      float e2 = bsrc[(size_t)(c15 + 32) * XS + xt] * BSCALE;
      float e3 = bsrc[(size_t)(c15 + 48) * XS + xt] * BSCALE;
      d0 = cvtpk(e0, e1); d1 = cvtpk(e2, e3);
    }
  };

  // ---- prefetch: e 4 steps deep; x as int4 double-buffered (4-step slack)
  unsigned er[4][4][2];
  i32x4 xq[4], xqn[4];
  int bj[4];
#pragma unroll
  for (int j = 0; j < 4; j++) {
    int tj0 = (c0 + 4 * g + j) * CHUNK - WARM;
#pragma unroll
    for (int u = 0; u < 4; u++)
      eload2(x[clamp01(tj0 + u)], er[u][j][0], er[u][j][1]);
    bj[j] = tj0 + 4;                               // xq base (mult of 4)
    xq[j] = *(const i32x4*)(x + clampB(bj[j]));    // x for steps 4..7
  }

  const f32x4 z4 = {0.f, 0.f, 0.f, 0.f};

  auto stepf = [&](int sabs, int u) {
    // A-frags (carry) from LDS: row = c15, k = 8g+j (+32 for half 1)
    const f32x4* wr = (const f32x4*)&wrow[c15][0];
    f32x4 q0 = wr[2 * g];
    f32x4 q1 = wr[2 * g + 1];
    f32x4 q2 = wr[2 * g + 8];
    f32x4 q3 = wr[2 * g + 9];
    union { u32x4 u4; bf16x8 b; } ua0, ua1;
    ua0.u4 = (u32x4){cvtpk(q0.x, q0.y), cvtpk(q0.z, q0.w), cvtpk(q1.x, q1.y), cvtpk(q1.z, q1.w)};
    ua1.u4 = (u32x4){cvtpk(q2.x, q2.y), cvtpk(q2.z, q2.w), cvtpk(q3.x, q3.y), cvtpk(q3.z, q3.w)};
    bf16x8 a0 = ua0.b, a1 = ua1.b;

    f32x4 C[4];
#pragma unroll
    for (int nt = 0; nt < 4; nt++) {
      f32x4 c = __builtin_amdgcn_mfma_f32_16x16x32_bf16(a0, Bhi[0][nt], z4, 0, 0, 0);
      c = __builtin_amdgcn_mfma_f32_16x16x32_bf16(a0, Blo[0][nt], c, 0, 0, 0);
      c = __builtin_amdgcn_mfma_f32_16x16x32_bf16(a1, Bhi[1][nt], c, 0, 0, 0);
      c = __builtin_amdgcn_mfma_f32_16x16x32_bf16(a1, Blo[1][nt], c, 0, 0, 0);
      C[nt] = c;
    }

    // w = C * e (e unpacked from bf16 pairs)
    float w[4][4]; // [nt][j]
#pragma unroll
    for (int j = 0; j < 4; j++) {
      unsigned d0 = er[u][j][0], d1 = er[u][j][1];
      w[0][j] = C[0][j] * bfu_lo(d0);
      w[1][j] = C[1][j] * bfu_hi(d0);
      w[2][j] = C[2][j] * bfu_lo(d1);
      w[3][j] = C[3][j] * bfu_hi(d1);
    }

    // chunk 0 (row 0 of wave 0): hold exact init until its t=0
    if (isw0 && sabs <= WARM) {
#pragma unroll
      for (int nt = 0; nt < 4; nt++)
        w[nt][0] = (lane < 16) ? o[nt] : w[nt][0];
    }

    // carry to LDS for next step's A-frags (wave-private, in-order DS)
#pragma unroll
    for (int j = 0; j < 4; j++)
#pragma unroll
      for (int nt = 0; nt < 4; nt++)
        wrow[g * 4 + j][16 * nt + c15] = w[nt][j];

    // refill rings: e for step sabs+4; x int4 once per macro (4-step slack)
#pragma unroll
    for (int j = 0; j < 4; j++) {
      eload2(xq[j][u], er[u][j][0], er[u][j][1]);
      if (u == 0) xqn[j] = *(const i32x4*)(x + clampB(bj[j] + 4));
    }

    // store path: read back carry in store layout (lane = row rr, quad qq)
    if (sabs >= WARM) {
      f32x4 v0 = *(const f32x4*)&wrow[rr][ 0 + 4 * qq];
      f32x4 v1 = *(const f32x4*)&wrow[rr][16 + 4 * qq];
      f32x4 v2 = *(const f32x4*)&wrow[rr][32 + 4 * qq];
      f32x4 v3 = *(const f32x4*)&wrow[rr][48 + 4 * qq];
      f32x4 vs = (v0 + v1) + (v2 + v3);
      float s = (vs.x + vs.y) + (vs.z + vs.w);
      s += __shfl_xor(s, 1);
      s += __shfl_xor(s, 2);
      float rs = __builtin_amdgcn_rcpf(s);
      if (trow < TLEN) {
        float* po = out + (size_t)trow * YS + 4 * qq;
        *(f32x4*)(po +  0) = v0 * rs;
        *(f32x4*)(po + 16) = v1 * rs;
        *(f32x4*)(po + 32) = v2 * rs;
        *(f32x4*)(po + 48) = v3 * rs;
      }
    }
    trow += 1;
  };

  for (int s = 0; s < SPAN; s += 4) {
    stepf(s + 0, 0);
    stepf(s + 1, 1);
    stepf(s + 2, 2);
    stepf(s + 3, 3);
#pragma unroll
    for (int j = 0; j < 4; j++) {
      xq[j] = xqn[j];
      bj[j] += 4;
    }
  }
}

// transpose+pack b (YS x XS f32) -> bpk (XS x 32 dwords), lane-adjacent layout:
// slot s2 = 2*c15 + p; p=0 -> cols (c15, c15+16), p=1 -> cols (c15+32, c15+48)
__global__ __launch_bounds__(256) void pack_b(
    const float* __restrict__ b, unsigned* __restrict__ bpk)
{
  __shared__ float tile[64][65];
  int x0 = blockIdx.x << 6;
  int lane = threadIdx.x & 63;
  int w = threadIdx.x >> 6;
  int xg = x0 + lane;
#pragma unroll
  for (int yy = 0; yy < 64; yy += 4) {
    int y = yy + w;
    tile[y][lane] = (xg < XS) ? b[(size_t)y * XS + xg] * BSCALE : 0.f;
  }
  __syncthreads();
  int s2 = threadIdx.x & 31;          // dword slot 0..31
  int xo = threadIdx.x >> 5;          // 0..7
  int c15 = s2 >> 1, p = s2 & 1;
  int colA = c15 + 32 * p, colB = colA + 16;
#pragma unroll
  for (int pass = 0; pass < 8; pass++) {
    int xl = pass * 8 + xo;
    int xcur = x0 + xl;
    if (xcur < XS)
      bpk[(size_t)xcur * 32 + s2] = cvtpk(tile[colA][xl], tile[colB][xl]);
  }
}

extern "C" void kernel_launch(void* const* d_in, const int* in_sizes, int n_in,
                              void* d_out, int out_size, void* d_ws, size_t ws_size,
                              hipStream_t stream)
{
  const int*   x  = (const int*)d_in[0];
  const float* A  = (const float*)d_in[1];
  const float* b  = (const float*)d_in[2];
  const float* pi = (const float*)d_in[3];
  float* out = (float*)d_out;

  const size_t bpk_bytes = (size_t)XS * 32 * sizeof(unsigned);  // 6.4 MB

  if (ws_size >= bpk_bytes) {
    unsigned* bpk = (unsigned*)d_ws;
    int tblocks = (XS + 63) / 64;
    pack_b<<<tblocks, 256, 0, stream>>>(b, bpk);
    hmm_fwd<true><<<NBLK, 256, 0, stream>>>(x, A, pi, b, bpk, out);
  } else {
    hmm_fwd<false><<<NBLK, 256, 0, stream>>>(x, A, pi, b, nullptr, out);
  }
}